// Round 1
// baseline (886.643 us; speedup 1.0000x reference)
//
#include <hip/hip_runtime.h>

#define HH_ 127
#define WW_ 127
#define C_  256
#define NH_ 4

typedef __attribute__((ext_vector_type(8))) __bf16 bf16x8;
typedef __attribute__((ext_vector_type(4))) float f32x4;
typedef unsigned short u16;
typedef __attribute__((ext_vector_type(4))) u16 u16x4;
typedef __attribute__((ext_vector_type(8))) u16 u16x8;

__device__ __forceinline__ float b2f(u16 u) {
    unsigned v = ((unsigned)u) << 16;
    return __builtin_bit_cast(float, v);
}
__device__ __forceinline__ u16 f2b(float f) {
    return __builtin_bit_cast(u16, (__bf16)f);
}
__device__ __forceinline__ bf16x8 zero8() {
    bf16x8 z;
#pragma unroll
    for (int i = 0; i < 8; ++i) z[i] = (__bf16)0.f;
    return z;
}

// LDS byte offsets
#define XN_OFF 0                   // 128 x 256 bf16 (rows 512B, xor-swizzled)
#define QH_OFF 65536               // 128 x 64 bf16 (rows 128B)
#define KH_OFF (65536 + 16384)
#define VT_OFF (65536 + 32768)     // 64 x 128 bf16 transposed (rows 256B)
#define OH_OFF (65536 + 49152)     // 128 x 64 bf16
#define PB_OFF (65536 + 65536)     // 8 waves x [16][16] bf16
#define LDS_SZ (65536 + 65536 + 4096)

__global__ void lwa_prep(const float* __restrict__ in_w, const float* __restrict__ out_w,
                         const float* __restrict__ proj_w, u16* __restrict__ ws) {
    int i = blockIdx.x * 256 + threadIdx.x;
    if (i < 196608) ws[i] = f2b(in_w[i]);
    if (i < 65536) {
        ws[196608 + i] = f2b(out_w[i]);
        ws[262144 + i] = f2b(proj_w[i]);
    }
}

__global__ __launch_bounds__(512, 2)
void lwa_main(const float* __restrict__ feat,
              const float* __restrict__ ln_w, const float* __restrict__ ln_b,
              const float* __restrict__ in_b, const float* __restrict__ out_b,
              const float* __restrict__ proj_b,
              const u16* __restrict__ w_in, const u16* __restrict__ w_out,
              const u16* __restrict__ w_proj,
              float* __restrict__ outp)
{
    __shared__ __align__(16) char smem[LDS_SZ];
    const int tid  = threadIdx.x;
    const int lane = tid & 63;
    const int wid  = tid >> 6;      // 0..7
    const int bid  = blockIdx.x;
    const int jh = bid & 3;         // 4 column-groups of 8 windows
    const int wi = (bid >> 2) & 31; // window row
    const int bb = bid >> 7;        // batch
    const int h0 = wi * 4;
    const int w0 = jh * 32;
    const size_t bbase = (size_t)bb * (C_ * HH_ * WW_);

    // ---------- Stage A: gather NCHW tile -> bf16 LDS (swizzled) ----------
    {
        const int wl = lane & 31;
        const int hl = lane >> 5;
#pragma unroll 4
        for (int it = 0; it < 64; ++it) {
            int pp = it * 16 + wid * 2 + hl;  // (c,hh) pair 0..1023
            int c = pp >> 2;
            int hh = pp & 3;
            int hcur = h0 + hh;
            int wcur = w0 + wl;
            float v = 0.f;
            if (hcur < HH_ && wcur < WW_)
                v = feat[bbase + (size_t)(c * HH_ + hcur) * WW_ + wcur];
            int m = (wl >> 2) * 16 + hh * 4 + (wl & 3);
            *(u16*)(smem + XN_OFF + m * 512 + ((2 * c) ^ ((m & 7) << 4))) = f2b(v);
        }
    }
    __syncthreads();

    // ---------- LayerNorm (4 threads per token) ----------
    {
        const int m = tid >> 2;
        const int qv = tid & 3;
        const int rowoff = XN_OFF + m * 512;
        const int sw = (m & 7) << 4;
        float s = 0.f, s2 = 0.f;
#pragma unroll
        for (int i = 0; i < 8; ++i) {
            int c0 = qv * 64 + i * 8;
            u16x8 u = *(u16x8*)(smem + rowoff + ((2 * c0) ^ sw));
#pragma unroll
            for (int e = 0; e < 8; ++e) { float f = b2f(u[e]); s += f; s2 += f * f; }
        }
        s  += __shfl_xor(s, 1);  s  += __shfl_xor(s, 2);
        s2 += __shfl_xor(s2, 1); s2 += __shfl_xor(s2, 2);
        float mu = s * (1.f / 256.f);
        float var = s2 * (1.f / 256.f) - mu * mu;
        float rs = rsqrtf(var + 1e-5f);
#pragma unroll
        for (int i = 0; i < 8; ++i) {
            int c0 = qv * 64 + i * 8;
            u16x8 u = *(u16x8*)(smem + rowoff + ((2 * c0) ^ sw));
            f32x4 lw0 = *(const f32x4*)(ln_w + c0);
            f32x4 lw1 = *(const f32x4*)(ln_w + c0 + 4);
            f32x4 lb0 = *(const f32x4*)(ln_b + c0);
            f32x4 lb1 = *(const f32x4*)(ln_b + c0 + 4);
            u16x8 o;
#pragma unroll
            for (int e = 0; e < 4; ++e) {
                o[e]     = f2b((b2f(u[e])     - mu) * rs * lw0[e] + lb0[e]);
                o[e + 4] = f2b((b2f(u[e + 4]) - mu) * rs * lw1[e] + lb1[e]);
            }
            *(u16x8*)(smem + rowoff + ((2 * c0) ^ sw)) = o;
        }
    }
    __syncthreads();

    const int mg = wid >> 2;   // 0..1  (M-group: 4 m-tiles each)
    const int ng = wid & 3;    // 0..3  (N-group)
    const int col = lane & 15;
    const int krow = lane >> 4;

    f32x4 acc_o[4][4];         // out-proj accumulator, summed over heads
#pragma unroll
    for (int a = 0; a < 4; ++a)
#pragma unroll
        for (int b = 0; b < 4; ++b) acc_o[a][b] = f32x4{0.f, 0.f, 0.f, 0.f};

    for (int hq = 0; hq < NH_; ++hq) {
        // ===== QKV (head hq): xn[128x256] @ in_w_slice^T -> q/k/v LDS =====
        {
            f32x4 acc[3][4];
#pragma unroll
            for (int nl = 0; nl < 3; ++nl)
#pragma unroll
                for (int mi = 0; mi < 4; ++mi) acc[nl][mi] = f32x4{0.f, 0.f, 0.f, 0.f};

            const u16* wptr[3];
            float bias[3];
#pragma unroll
            for (int nl = 0; nl < 3; ++nl) {
                int nt = ng * 3 + nl;            // 0..11
                int sec = nt >> 2, d16 = nt & 3; // q/k/v , 16-col group
                int wr = sec * 256 + hq * 64 + d16 * 16 + col;
                wptr[nl] = w_in + (size_t)wr * 256 + krow * 8;
                bias[nl] = in_b[wr];
            }
            bf16x8 bcur[3], bnxt[3];
#pragma unroll
            for (int nl = 0; nl < 3; ++nl) bcur[nl] = *(const bf16x8*)(wptr[nl]);
#pragma unroll
            for (int k = 0; k < 8; ++k) {
                if (k < 7) {
#pragma unroll
                    for (int nl = 0; nl < 3; ++nl)
                        bnxt[nl] = *(const bf16x8*)(wptr[nl] + (k + 1) * 32);
                }
                bf16x8 a[4];
#pragma unroll
                for (int mi = 0; mi < 4; ++mi) {
                    int row = (mg * 4 + mi) * 16 + col;
                    a[mi] = *(const bf16x8*)(smem + XN_OFF + row * 512 +
                                             ((k * 64 + krow * 16) ^ ((row & 7) << 4)));
                }
#pragma unroll
                for (int nl = 0; nl < 3; ++nl)
#pragma unroll
                    for (int mi = 0; mi < 4; ++mi)
                        acc[nl][mi] = __builtin_amdgcn_mfma_f32_16x16x32_bf16(a[mi], bcur[nl], acc[nl][mi], 0, 0, 0);
                if (k < 7) {
#pragma unroll
                    for (int nl = 0; nl < 3; ++nl) bcur[nl] = bnxt[nl];
                }
            }
#pragma unroll
            for (int nl = 0; nl < 3; ++nl) {
                int nt = ng * 3 + nl;
                int sec = nt >> 2, d16 = nt & 3;
                int d = d16 * 16 + col;
#pragma unroll
                for (int mi = 0; mi < 4; ++mi) {
#pragma unroll
                    for (int r = 0; r < 4; ++r) {
                        int m = (mg * 4 + mi) * 16 + krow * 4 + r;
                        u16 hv = f2b(acc[nl][mi][r] + bias[nl]);
                        if (sec == 0)
                            *(u16*)(smem + QH_OFF + m * 128 + ((2 * d) ^ ((m & 7) << 4))) = hv;
                        else if (sec == 1)
                            *(u16*)(smem + KH_OFF + m * 128 + ((2 * d) ^ ((m & 7) << 4))) = hv;
                        else  // v stored transposed: VT[d][m]
                            *(u16*)(smem + VT_OFF + d * 256 + ((2 * m) ^ ((d & 7) << 4))) = hv;
                    }
                }
            }
        }
        __syncthreads();

        // ===== attention (head hq): wave wid owns window wid =====
        {
            const int m0 = wid * 16;
            f32x4 sacc = f32x4{0.f, 0.f, 0.f, 0.f};
            int rowq = m0 + col;
            int rsw = (rowq & 7) << 4;
#pragma unroll
            for (int ks = 0; ks < 2; ++ks) {   // scores^T = K @ Q^T over d=64
                int doff = ks * 64 + krow * 16;
                bf16x8 af  = *(const bf16x8*)(smem + KH_OFF + rowq * 128 + (doff ^ rsw));
                bf16x8 bfq = *(const bf16x8*)(smem + QH_OFF + rowq * 128 + (doff ^ rsw));
                sacc = __builtin_amdgcn_mfma_f32_16x16x32_bf16(af, bfq, sacc, 0, 0, 0);
            }
            // D layout: row=k'=(krow*4+r), col=q. Softmax over k' per q-column.
            float s0 = sacc[0] * 0.125f, s1 = sacc[1] * 0.125f;
            float s2 = sacc[2] * 0.125f, s3 = sacc[3] * 0.125f;
            float mx = fmaxf(fmaxf(s0, s1), fmaxf(s2, s3));
            mx = fmaxf(mx, __shfl_xor(mx, 16));
            mx = fmaxf(mx, __shfl_xor(mx, 32));
            float p0 = __expf(s0 - mx), p1 = __expf(s1 - mx);
            float p2 = __expf(s2 - mx), p3 = __expf(s3 - mx);
            float sm = p0 + p1 + p2 + p3;
            sm += __shfl_xor(sm, 16);
            sm += __shfl_xor(sm, 32);
            float inv = 1.f / sm;
            p0 *= inv; p1 *= inv; p2 *= inv; p3 *= inv;
            // store P[q][k'] tile (bf16, [16][16])
            unsigned pk0 = (unsigned)f2b(p0) | ((unsigned)f2b(p1) << 16);
            unsigned pk1 = (unsigned)f2b(p2) | ((unsigned)f2b(p3) << 16);
            int pbase = PB_OFF + wid * 512 + col * 32 + krow * 8;
            *(unsigned*)(smem + pbase) = pk0;
            *(unsigned*)(smem + pbase + 4) = pk1;
            // PV: A=P (k padded to 32 with zeros), B=V^T reads (contiguous)
            bf16x8 pa = zero8();
            if (lane < 32)
                pa = *(const bf16x8*)(smem + PB_OFF + wid * 512 + col * 32 + krow * 16);
#pragma unroll
            for (int nt = 0; nt < 4; ++nt) {
                bf16x8 bv = zero8();
                int d = nt * 16 + col;
                if (lane < 32) {
                    int mm = m0 + krow * 8;
                    bv = *(const bf16x8*)(smem + VT_OFF + d * 256 + ((2 * mm) ^ ((d & 7) << 4)));
                }
                f32x4 oz = f32x4{0.f, 0.f, 0.f, 0.f};
                f32x4 oacc = __builtin_amdgcn_mfma_f32_16x16x32_bf16(pa, bv, oz, 0, 0, 0);
#pragma unroll
                for (int r = 0; r < 4; ++r) {
                    int m = m0 + krow * 4 + r;
                    *(u16*)(smem + OH_OFF + m * 128 + ((2 * d) ^ ((m & 7) << 4))) = f2b(oacc[r]);
                }
            }
        }
        __syncthreads();

        // ===== out-proj partial (accumulate over heads in regs) =====
        {
#pragma unroll
            for (int k = 0; k < 2; ++k) {
                bf16x8 a[4];
#pragma unroll
                for (int mi = 0; mi < 4; ++mi) {
                    int row = (mg * 4 + mi) * 16 + col;
                    a[mi] = *(const bf16x8*)(smem + OH_OFF + row * 128 +
                                             ((k * 64 + krow * 16) ^ ((row & 7) << 4)));
                }
#pragma unroll
                for (int nl = 0; nl < 4; ++nl) {
                    int n = (ng * 4 + nl) * 16 + col;
                    bf16x8 bw = *(const bf16x8*)(w_out + (size_t)n * 256 + hq * 64 + k * 32 + krow * 8);
#pragma unroll
                    for (int mi = 0; mi < 4; ++mi)
                        acc_o[nl][mi] = __builtin_amdgcn_mfma_f32_16x16x32_bf16(a[mi], bw, acc_o[nl][mi], 0, 0, 0);
                }
            }
        }
        // no barrier needed: next QKV writes QH/KH/VT only; OH rewritten after next barrier
    }

    // ===== ob = acc_o + out_b  -> XN buffer (bf16) =====
    {
#pragma unroll
        for (int nl = 0; nl < 4; ++nl) {
            int n = (ng * 4 + nl) * 16 + col;
            float bo = out_b[n];
#pragma unroll
            for (int mi = 0; mi < 4; ++mi) {
#pragma unroll
                for (int r = 0; r < 4; ++r) {
                    int m = (mg * 4 + mi) * 16 + krow * 4 + r;
                    *(u16*)(smem + XN_OFF + m * 512 + ((2 * n) ^ ((m & 7) << 4))) =
                        f2b(acc_o[nl][mi][r] + bo);
                }
            }
        }
    }
    __syncthreads();

    // ===== proj + GELU + residual + store =====
    {
        f32x4 pacc[4][4];
#pragma unroll
        for (int a = 0; a < 4; ++a)
#pragma unroll
            for (int b = 0; b < 4; ++b) pacc[a][b] = f32x4{0.f, 0.f, 0.f, 0.f};
#pragma unroll
        for (int k = 0; k < 8; ++k) {
            bf16x8 a[4];
#pragma unroll
            for (int mi = 0; mi < 4; ++mi) {
                int row = (mg * 4 + mi) * 16 + col;
                a[mi] = *(const bf16x8*)(smem + XN_OFF + row * 512 +
                                         ((k * 64 + krow * 16) ^ ((row & 7) << 4)));
            }
#pragma unroll
            for (int nl = 0; nl < 4; ++nl) {
                int n = (ng * 4 + nl) * 16 + col;
                bf16x8 bw = *(const bf16x8*)(w_proj + (size_t)n * 256 + k * 32 + krow * 8);
#pragma unroll
                for (int mi = 0; mi < 4; ++mi)
                    pacc[nl][mi] = __builtin_amdgcn_mfma_f32_16x16x32_bf16(a[mi], bw, pacc[nl][mi], 0, 0, 0);
            }
        }
        const int hcur = h0 + krow;   // ti = krow
#pragma unroll
        for (int nl = 0; nl < 4; ++nl) {
            int n = (ng * 4 + nl) * 16 + col;   // channel
            float pb = proj_b[n];
#pragma unroll
            for (int mi = 0; mi < 4; ++mi) {
                int mt = mg * 4 + mi;           // window within block
                int wbase = w0 + mt * 4;
                if (hcur < HH_) {
                    size_t g = bbase + (size_t)(n * HH_ + hcur) * WW_ + wbase;
                    int wlim = WW_ - wbase;
#pragma unroll
                    for (int r = 0; r < 4; ++r) {
                        if (r < wlim) {
                            float x = pacc[nl][mi][r] + pb;
                            float ge = 0.5f * x * (1.f + erff(x * 0.70710678118f));
                            outp[g + r] = feat[g + r] + ge;
                        }
                    }
                }
            }
        }
    }
}

extern "C" void kernel_launch(void* const* d_in, const int* in_sizes, int n_in,
                              void* d_out, int out_size, void* d_ws, size_t ws_size,
                              hipStream_t stream) {
    const float* feat   = (const float*)d_in[0];
    const float* ln_w   = (const float*)d_in[1];
    const float* ln_b   = (const float*)d_in[2];
    const float* in_w   = (const float*)d_in[3];
    const float* in_b   = (const float*)d_in[4];
    const float* out_w  = (const float*)d_in[5];
    const float* out_b  = (const float*)d_in[6];
    const float* proj_w = (const float*)d_in[7];
    const float* proj_b = (const float*)d_in[8];
    u16* wsp = (u16*)d_ws;   // bf16 weights: in_w[196608] | out_w[65536] | proj_w[65536]

    lwa_prep<<<768, 256, 0, stream>>>(in_w, out_w, proj_w, wsp);
    lwa_main<<<1024, 512, 0, stream>>>(feat, ln_w, ln_b, in_b, out_b, proj_b,
                                       wsp, wsp + 196608, wsp + 262144,
                                       (float*)d_out);
}

// Round 2
// 462.065 us; speedup vs baseline: 1.9189x; 1.9189x over previous
//
#include <hip/hip_runtime.h>

typedef _Float16 f16;
typedef __attribute__((ext_vector_type(4))) _Float16 half4;
typedef __attribute__((ext_vector_type(8))) _Float16 half8;
typedef __attribute__((ext_vector_type(4))) float f32x4;
typedef unsigned short u16;

#define MFMA32(a,b,c) __builtin_amdgcn_mfma_f32_16x16x32_f16(a,b,c,0,0,0)
#define MFMA16(a,b,c) __builtin_amdgcn_mfma_f32_16x16x16f16(a,b,c,0,0,0)

// ws layout (f16 element offsets)
#define W_IN0   0
#define W_OUT0  196608
#define W_PROJ0 262144
#define X0      327680
#define QK0     33882112ull
#define VT0     100990976ull

// ---------------- k0: cast weights to f16 ----------------
__global__ void k0_cast(const float* __restrict__ iw, const float* __restrict__ ow,
                        const float* __restrict__ pw, f16* __restrict__ W) {
    int i = blockIdx.x * 256 + threadIdx.x;
    if (i < 196608) W[W_IN0 + i] = (f16)iw[i];
    if (i < 65536) {
        W[W_OUT0 + i]  = (f16)ow[i];
        W[W_PROJ0 + i] = (f16)pw[i];
    }
}

// ---------------- k1: NCHW gather + LayerNorm -> X[t][256] f16 ----------------
__global__ __launch_bounds__(256, 2)
void k1_pack(const float* __restrict__ feat, const float* __restrict__ lnw,
             const float* __restrict__ lnb, f16* __restrict__ X) {
    __shared__ __align__(16) char sm[65536];   // [128 rows][512B] swizzled gran16 by (m&7)
    const int tid = threadIdx.x, lane = tid & 63;
    const int bid = blockIdx.x;
    const int jh = bid & 3, wi = (bid >> 2) & 31, bb = bid >> 7;
    const int h0 = wi * 4, w0 = jh * 32;
    const size_t bbase = (size_t)bb * 256 * 127 * 127;
    const int wl = lane & 31;
    const int pg = tid >> 5;   // 0..7
#pragma unroll 4
    for (int it = 0; it < 128; ++it) {
        int pp = it * 8 + pg;          // 0..1023 (c,hh)
        int cc = pp >> 2, hh = pp & 3;
        int hcur = h0 + hh, wcur = w0 + wl;
        float v = 0.f;
        if (hcur < 127 && wcur < 127)
            v = feat[bbase + (size_t)(cc * 127 + hcur) * 127 + wcur];
        int m = (wl >> 2) * 16 + hh * 4 + (wl & 3);
        *(f16*)(sm + m * 512 + ((2 * cc) ^ ((m & 7) << 4))) = (f16)v;
    }
    __syncthreads();
    const int m = tid >> 1, hf = tid & 1;
    const int sw = (m & 7) << 4;
    char* rowp = sm + m * 512;
    float s = 0.f, s2 = 0.f;
    half8 vv[16];
#pragma unroll
    for (int i = 0; i < 16; ++i) {
        int c0 = hf * 128 + i * 8;
        half8 u = *(half8*)(rowp + ((2 * c0) ^ sw));
        vv[i] = u;
#pragma unroll
        for (int e = 0; e < 8; ++e) { float f = (float)u[e]; s += f; s2 += f * f; }
    }
    s  += __shfl_xor(s, 1);
    s2 += __shfl_xor(s2, 1);
    float mu = s * (1.f / 256.f);
    float rs = rsqrtf(s2 * (1.f / 256.f) - mu * mu + 1e-5f);
    f16* xrow = X + ((size_t)bid * 128 + m) * 256 + hf * 128;
#pragma unroll
    for (int i = 0; i < 16; ++i) {
        int c0 = hf * 128 + i * 8;
        f32x4 lw0 = *(const f32x4*)(lnw + c0);
        f32x4 lw1 = *(const f32x4*)(lnw + c0 + 4);
        f32x4 lb0 = *(const f32x4*)(lnb + c0);
        f32x4 lb1 = *(const f32x4*)(lnb + c0 + 4);
        half8 o;
#pragma unroll
        for (int e = 0; e < 4; ++e) {
            o[e]     = (f16)(((float)vv[i][e]     - mu) * rs * lw0[e] + lb0[e]);
            o[e + 4] = (f16)(((float)vv[i][e + 4] - mu) * rs * lw1[e] + lb1[e]);
        }
        *(half8*)(xrow + i * 8) = o;
    }
}

// ---------------- k2: QKV GEMM  X[131072x256] @ in_w^T -> QK / VT ----------------
__global__ __launch_bounds__(256, 2)
void k2_qkv(const f16* __restrict__ X, const f16* __restrict__ win,
            const float* __restrict__ inb, f16* __restrict__ QK, f16* __restrict__ VT) {
    __shared__ __align__(16) char sm[65536];   // 2 bufs x (A 16K | B 16K)
    const int tid = threadIdx.x, lane = tid & 63, wv = tid >> 6;
    const int bid = blockIdx.x;
    const int mt = bid / 6, nb = bid % 6;
    const size_t Mbase = (size_t)mt * 128;
    const int n0 = nb * 128;
    const int wm = wv >> 1, wn = wv & 1;
    const int c = lane & 15, g = lane >> 4;
    const int r8 = lane >> 3, chv = lane & 7;

    f32x4 acc[4][4];
#pragma unroll
    for (int a = 0; a < 4; ++a)
#pragma unroll
        for (int b = 0; b < 4; ++b) acc[a][b] = f32x4{0.f, 0.f, 0.f, 0.f};

    auto stage = [&](int step, int bsel) {
        const f16* As = X + Mbase * 256 + step * 64;
        const f16* Bs = win + (size_t)n0 * 256 + step * 64;
#pragma unroll
        for (int q = 0; q < 4; ++q) {
            int ia = wv * 4 + q;
            int row = ia * 8 + r8;
            int chs = chv ^ (row & 7);
            __builtin_amdgcn_global_load_lds(
                (const __attribute__((address_space(1))) unsigned int*)(As + (size_t)row * 256 + chs * 8),
                (__attribute__((address_space(3))) unsigned int*)(sm + bsel * 32768 + ia * 1024),
                16, 0, 0);
            __builtin_amdgcn_global_load_lds(
                (const __attribute__((address_space(1))) unsigned int*)(Bs + (size_t)row * 256 + chs * 8),
                (__attribute__((address_space(3))) unsigned int*)(sm + bsel * 32768 + 16384 + ia * 1024),
                16, 0, 0);
        }
    };
    stage(0, 0);
    __syncthreads();
    for (int s = 0; s < 4; ++s) {
        int bsel = s & 1;
        if (s < 3) stage(s + 1, bsel ^ 1);
#pragma unroll
        for (int kk2 = 0; kk2 < 2; ++kk2) {
            half8 a[4], b[4];
#pragma unroll
            for (int mi = 0; mi < 4; ++mi) {
                int row = wm * 64 + mi * 16 + c;
                a[mi] = *(half8*)(sm + bsel * 32768 + row * 128 + ((kk2 * 64 + g * 16) ^ ((row & 7) << 4)));
            }
#pragma unroll
            for (int nt = 0; nt < 4; ++nt) {
                int row = wn * 64 + nt * 16 + c;
                b[nt] = *(half8*)(sm + bsel * 32768 + 16384 + row * 128 + ((kk2 * 64 + g * 16) ^ ((row & 7) << 4)));
            }
#pragma unroll
            for (int mi = 0; mi < 4; ++mi)
#pragma unroll
                for (int nt = 0; nt < 4; ++nt)
                    acc[mi][nt] = MFMA32(a[mi], b[nt], acc[mi][nt]);
        }
        __syncthreads();
    }

    const f32x4 z4 = {0.f, 0.f, 0.f, 0.f};
    half4 idf;
#pragma unroll
    for (int j = 0; j < 4; ++j) idf[j] = (f16)((g * 4 + j == c) ? 1.f : 0.f);

    if (n0 < 512) {
        // Q,K: transpose via identity mfma, store row-major QK[t][512]
#pragma unroll
        for (int mi = 0; mi < 4; ++mi)
#pragma unroll
            for (int nt = 0; nt < 4; ++nt) {
                int n = n0 + wn * 64 + nt * 16 + c;
                float bias = inb[n];
                half4 h;
#pragma unroll
                for (int r = 0; r < 4; ++r) h[r] = (f16)(acc[mi][nt][r] + bias);
                f32x4 t = MFMA16(h, idf, z4);      // C/D-as-A (=T^T) times I -> transposed tile
                half4 o;
#pragma unroll
                for (int r = 0; r < 4; ++r) o[r] = (f16)t[r];
                size_t tok = Mbase + wm * 64 + mi * 16 + c;       // col of transposed tile = m
                *(half4*)(QK + tok * 512 + (n0 + wn * 64 + nt * 16 + g * 4)) = o;
            }
    } else {
        // V: store [win][d][t] directly from C/D (rows = 4 contiguous tokens)
#pragma unroll
        for (int mi = 0; mi < 4; ++mi)
#pragma unroll
            for (int nt = 0; nt < 4; ++nt) {
                int n = n0 + wn * 64 + nt * 16 + c;
                float bias = inb[n];
                half4 h;
#pragma unroll
                for (int r = 0; r < 4; ++r) h[r] = (f16)(acc[mi][nt][r] + bias);
                int d = n - 512;
                size_t tokb = Mbase + wm * 64 + mi * 16;          // window-aligned
                size_t winI = tokb >> 4;
                *(half4*)(VT + winI * 4096 + (size_t)d * 16 + g * 4) = h;
            }
    }
}

// ---------------- k3: attention + out-proj + proj + GELU -> G[t][256] f16 ----------------
__global__ __launch_bounds__(256, 3)
void k3_attn(const f16* __restrict__ QK, const f16* __restrict__ VT,
             const f16* __restrict__ wout, const f16* __restrict__ wproj,
             const float* __restrict__ outb, const float* __restrict__ projb,
             f16* __restrict__ G) {
    __shared__ __align__(16) char sm[32768];   // 2 x 16KB weight chunks [32 n][256 d], 8B-XOR swizzled
    const int tid = threadIdx.x, lane = tid & 63, wv = tid >> 6;
    const int c = lane & 15, g = lane >> 4;
    const size_t win = (size_t)blockIdx.x * 4 + wv;
    const f16* qrow = QK + (win * 16 + c) * 512;
    const f32x4 z4 = {0.f, 0.f, 0.f, 0.f};

    const int nl = tid >> 3, seg = tid & 7;
    const int swz = (nl & 7) << 3;
    auto stageW = [&](const f16* mat, int rc, int bsel) {
        const f16* src = mat + ((size_t)(rc * 32 + nl)) * 256 + seg * 32;
        char* dst = sm + bsel * 16384 + nl * 512;
#pragma unroll
        for (int i = 0; i < 4; ++i) {
            uint4 u = *(const uint4*)(src + i * 8);
            int b0 = (seg * 64 + i * 16) ^ swz;
            int b1 = (seg * 64 + i * 16 + 8) ^ swz;
            *(uint2*)(dst + b0) = make_uint2(u.x, u.y);
            *(uint2*)(dst + b1) = make_uint2(u.z, u.w);
        }
    };

    stageW(wout, 0, 0);   // chunk 0 in flight under attention

    // ---- attention, all in registers ----
    half4 of16[4][4];
#pragma unroll
    for (int hq = 0; hq < 4; ++hq) {
        half8 af0 = *(const half8*)(qrow + 256 + hq * 64 + g * 8);
        half8 af1 = *(const half8*)(qrow + 256 + hq * 64 + 32 + g * 8);
        half8 bq0 = *(const half8*)(qrow + hq * 64 + g * 8);
        half8 bq1 = *(const half8*)(qrow + hq * 64 + 32 + g * 8);
        f32x4 sacc = MFMA32(af0, bq0, z4);     // S^T[k_tok][q]
        sacc = MFMA32(af1, bq1, sacc);
        float s0 = sacc[0] * 0.125f, s1 = sacc[1] * 0.125f;
        float s2 = sacc[2] * 0.125f, s3 = sacc[3] * 0.125f;
        float mx = fmaxf(fmaxf(s0, s1), fmaxf(s2, s3));
        mx = fmaxf(mx, __shfl_xor(mx, 16));
        mx = fmaxf(mx, __shfl_xor(mx, 32));
        float p0 = __expf(s0 - mx), p1 = __expf(s1 - mx);
        float p2 = __expf(s2 - mx), p3 = __expf(s3 - mx);
        float sum = p0 + p1 + p2 + p3;
        sum += __shfl_xor(sum, 16);
        sum += __shfl_xor(sum, 32);
        float inv = 1.f / sum;
        half4 pf;
        pf[0] = (f16)(p0 * inv); pf[1] = (f16)(p1 * inv);
        pf[2] = (f16)(p2 * inv); pf[3] = (f16)(p3 * inv);
#pragma unroll
        for (int nt = 0; nt < 4; ++nt) {
            half4 vf = *(const half4*)(VT + win * 4096 + (size_t)(hq * 64 + nt * 16 + c) * 16 + g * 4);
            f32x4 o = MFMA16(vf, pf, z4);      // O^T[d][q]
            half4 oh;
#pragma unroll
            for (int r = 0; r < 4; ++r) oh[r] = (f16)o[r];
            of16[hq][nt] = oh;
        }
    }

    // ---- out-proj: OB^T[n][q] accumulated over 16 chunks of w_out rows ----
    f32x4 obacc[16];
#pragma unroll
    for (int i = 0; i < 16; ++i) obacc[i] = z4;
    __syncthreads();
#pragma unroll
    for (int ch = 0; ch < 8; ++ch) {
        if (ch < 7) stageW(wout, ch + 1, (ch + 1) & 1);
        else        stageW(wproj, 0, (ch + 1) & 1);
        int bsel = ch & 1;
#pragma unroll
        for (int ntl = 0; ntl < 2; ++ntl) {
            int nt2 = ch * 2 + ntl;
            int rowl = ntl * 16 + c;
            char* base = sm + bsel * 16384 + rowl * 512;
            int sw2 = (rowl & 7) << 3;
            f32x4 a = obacc[nt2];
#pragma unroll
            for (int hq = 0; hq < 4; ++hq)
#pragma unroll
                for (int dt = 0; dt < 4; ++dt) {
                    half4 wf = *(const half4*)(base + (((hq * 64 + dt * 16 + g * 4) * 2) ^ sw2));
                    a = MFMA16(wf, of16[hq][dt], a);
                }
            obacc[nt2] = a;
        }
        __syncthreads();
    }
    half4 obT[16];
#pragma unroll
    for (int nt = 0; nt < 16; ++nt) {
        f32x4 bv = *(const f32x4*)(outb + nt * 16 + g * 4);
        half4 h;
#pragma unroll
        for (int r = 0; r < 4; ++r) h[r] = (f16)(obacc[nt][r] + bv[r]);
        obT[nt] = h;
    }

    // ---- proj: Y^T[n_out][q] over 8 chunks of w_proj rows ----
    f32x4 yacc[16];
#pragma unroll
    for (int i = 0; i < 16; ++i) yacc[i] = z4;
#pragma unroll
    for (int pc = 0; pc < 8; ++pc) {
        if (pc < 7) stageW(wproj, pc + 1, (pc + 1) & 1);
        int bsel = pc & 1;
#pragma unroll
        for (int ntl = 0; ntl < 2; ++ntl) {
            int nt3 = pc * 2 + ntl;
            int rowl = ntl * 16 + c;
            char* base = sm + bsel * 16384 + rowl * 512;
            int sw2 = (rowl & 7) << 3;
            f32x4 a = yacc[nt3];
#pragma unroll
            for (int ntc = 0; ntc < 16; ++ntc) {
                half4 wf = *(const half4*)(base + (((ntc * 16 + g * 4) * 2) ^ sw2));
                a = MFMA16(wf, obT[ntc], a);
            }
            yacc[nt3] = a;
        }
        __syncthreads();
    }

    // ---- bias + exact GELU + store G ----
#pragma unroll
    for (int nt = 0; nt < 16; ++nt) {
        f32x4 bv = *(const f32x4*)(projb + nt * 16 + g * 4);
        half4 h;
#pragma unroll
        for (int r = 0; r < 4; ++r) {
            float x = yacc[nt][r] + bv[r];
            h[r] = (f16)(0.5f * x * (1.f + erff(x * 0.70710678118f)));
        }
        *(half4*)(G + (win * 16 + c) * 256 + nt * 16 + g * 4) = h;
    }
}

// ---------------- k4: residual + NCHW scatter ----------------
__global__ __launch_bounds__(256, 2)
void k4_out(const f16* __restrict__ G, const float* __restrict__ feat, float* __restrict__ outp) {
    __shared__ __align__(16) char sm[65536];   // [128 w][512B] swizzled gran16 by (w&7)
    const int tid = threadIdx.x, lane = tid & 63, wv = tid >> 6;
    const int bid = blockIdx.x;
    const int bb = bid / 127, h = bid % 127;
    const size_t tb = (size_t)bb * 1024 + (size_t)(h >> 2) * 32;
    const int ti0 = (h & 3) * 4;
    const int j = tid >> 3, sc = tid & 7;
#pragma unroll
    for (int e = 0; e < 4; ++e) {
        size_t t = (tb + j) * 16 + ti0 + e;
        int wrow = j * 4 + e;
        const f16* gr = G + t * 256 + sc * 32;
        char* dr = sm + wrow * 512;
        int swz = (wrow & 7) << 4;
#pragma unroll
        for (int i = 0; i < 4; ++i) {
            uint4 u = *(const uint4*)(gr + i * 8);
            *(uint4*)(dr + ((sc * 64 + i * 16) ^ swz)) = u;
        }
    }
    __syncthreads();
    const int whalf = wv & 1, chalf = wv >> 1;
    const int w = whalf * 64 + lane;
    const bool wok = w < 127;
    const size_t obase = (size_t)bb * 256 * 127 * 127;
    const int wsw = (w & 7) << 4;
    for (int ci = 0; ci < 128; ++ci) {
        int cc = chalf * 128 + ci;
        f16 hv = *(const f16*)(sm + w * 512 + ((2 * cc) ^ wsw));
        if (wok) {
            size_t gidx = obase + (size_t)(cc * 127 + h) * 127 + w;
            outp[gidx] = feat[gidx] + (float)hv;
        }
    }
}

extern "C" void kernel_launch(void* const* d_in, const int* in_sizes, int n_in,
                              void* d_out, int out_size, void* d_ws, size_t ws_size,
                              hipStream_t stream) {
    const float* feat   = (const float*)d_in[0];
    const float* ln_w   = (const float*)d_in[1];
    const float* ln_b   = (const float*)d_in[2];
    const float* in_w   = (const float*)d_in[3];
    const float* in_b   = (const float*)d_in[4];
    const float* out_w  = (const float*)d_in[5];
    const float* out_b  = (const float*)d_in[6];
    const float* proj_w = (const float*)d_in[7];
    const float* proj_b = (const float*)d_in[8];

    f16* W  = (f16*)d_ws;
    f16* Xb  = W + X0;
    f16* QKb = W + QK0;
    f16* VTb = W + VT0;
    f16* Gb  = Xb;   // reuse X region for G (X dead after k2)

    k0_cast<<<768, 256, 0, stream>>>(in_w, out_w, proj_w, W);
    k1_pack<<<1024, 256, 0, stream>>>(feat, ln_w, ln_b, Xb);
    k2_qkv<<<6144, 256, 0, stream>>>(Xb, W + W_IN0, in_b, QKb, VTb);
    k3_attn<<<2048, 256, 0, stream>>>(QKb, VTb, W + W_OUT0, W + W_PROJ0, out_b, proj_b, Gb);
    k4_out<<<1016, 256, 0, stream>>>(Gb, feat, (float*)d_out);
}

// Round 3
// 461.595 us; speedup vs baseline: 1.9208x; 1.0010x over previous
//
#include <hip/hip_runtime.h>

typedef _Float16 f16;
typedef __attribute__((ext_vector_type(4))) _Float16 half4;
typedef __attribute__((ext_vector_type(8))) _Float16 half8;
typedef __attribute__((ext_vector_type(4))) float f32x4;
typedef unsigned short u16;

#define MFMA32(a,b,c) __builtin_amdgcn_mfma_f32_16x16x32_f16(a,b,c,0,0,0)
#define MFMA16(a,b,c) __builtin_amdgcn_mfma_f32_16x16x16f16(a,b,c,0,0,0)

// ws layout (f16 element offsets)
#define W_IN0   0
#define W_OUT0  196608
#define W_PROJ0 262144
#define X0      327680
#define QK0     33882112ull
#define VT0     100990976ull

// ---------------- k0: cast weights to f16 ----------------
__global__ void k0_cast(const float* __restrict__ iw, const float* __restrict__ ow,
                        const float* __restrict__ pw, f16* __restrict__ W) {
    int i = blockIdx.x * 256 + threadIdx.x;
    if (i < 196608) W[W_IN0 + i] = (f16)iw[i];
    if (i < 65536) {
        W[W_OUT0 + i]  = (f16)ow[i];
        W[W_PROJ0 + i] = (f16)pw[i];
    }
}

// ---------------- k1: NCHW gather + LayerNorm -> X[t][256] f16 (no LDS) ----------------
// thread = (token m, channel-half hf). wave = one hh row of the 4x32 strip.
// Per channel, 32 wl-lanes read 32 consecutive w -> 128B segments. LN stats in regs.
__global__ __launch_bounds__(256, 4)
void k1_pack(const float* __restrict__ feat, const float* __restrict__ lnw,
             const float* __restrict__ lnb, f16* __restrict__ X) {
    const int tid = threadIdx.x, lane = tid & 63, wid = tid >> 6;
    const int bid = blockIdx.x;
    const int jh = bid & 3, wi = (bid >> 2) & 31, bb = bid >> 7;
    const int h0 = wi * 4, w0 = jh * 32;
    const int wl = lane >> 1, hf = lane & 1;
    const int hh = wid;                  // wave id = row within window strip
    const int h = h0 + hh, w = w0 + wl;
    const bool ok = (h < 127) && (w < 127);
    const size_t bbase = (size_t)bb * (256 * 127 * 127);
    const float* p0 = feat + bbase + (size_t)(hf * 128) * 16129 + (size_t)h * 127 + w;

    half4 vv[32];
    float s = 0.f, s2 = 0.f;
    if (ok) {
#pragma unroll 4
        for (int i = 0; i < 32; ++i) {
            float v0 = p0[(size_t)(i * 4 + 0) * 16129];
            float v1 = p0[(size_t)(i * 4 + 1) * 16129];
            float v2 = p0[(size_t)(i * 4 + 2) * 16129];
            float v3 = p0[(size_t)(i * 4 + 3) * 16129];
            s  += v0 + v1 + v2 + v3;
            s2 += v0 * v0 + v1 * v1 + v2 * v2 + v3 * v3;
            half4 h4;
            h4[0] = (f16)v0; h4[1] = (f16)v1; h4[2] = (f16)v2; h4[3] = (f16)v3;
            vv[i] = h4;
        }
    } else {
#pragma unroll
        for (int i = 0; i < 32; ++i) {
            half4 h4;
            h4[0] = (f16)0.f; h4[1] = (f16)0.f; h4[2] = (f16)0.f; h4[3] = (f16)0.f;
            vv[i] = h4;
        }
    }
    s  += __shfl_xor(s, 1);
    s2 += __shfl_xor(s2, 1);
    float mu = s * (1.f / 256.f);
    float rs = rsqrtf(s2 * (1.f / 256.f) - mu * mu + 1e-5f);

    const int m = (wl >> 2) * 16 + hh * 4 + (wl & 3);
    f16* xrow = X + ((size_t)bid * 128 + m) * 256 + hf * 128;
#pragma unroll
    for (int i = 0; i < 16; ++i) {
        int c0 = hf * 128 + i * 8;
        f32x4 lw0 = *(const f32x4*)(lnw + c0);
        f32x4 lw1 = *(const f32x4*)(lnw + c0 + 4);
        f32x4 lb0 = *(const f32x4*)(lnb + c0);
        f32x4 lb1 = *(const f32x4*)(lnb + c0 + 4);
        half8 o;
#pragma unroll
        for (int e = 0; e < 4; ++e) {
            o[e]     = (f16)(((float)vv[2 * i][e]     - mu) * rs * lw0[e] + lb0[e]);
            o[e + 4] = (f16)(((float)vv[2 * i + 1][e] - mu) * rs * lw1[e] + lb1[e]);
        }
        *(half8*)(xrow + i * 8) = o;
    }
}

// ---------------- k2: QKV GEMM  X[131072x256] @ in_w^T -> QK / VT ----------------
__global__ __launch_bounds__(256, 2)
void k2_qkv(const f16* __restrict__ X, const f16* __restrict__ win,
            const float* __restrict__ inb, f16* __restrict__ QK, f16* __restrict__ VT) {
    __shared__ __align__(16) char sm[65536];   // 2 bufs x (A 16K | B 16K)
    const int tid = threadIdx.x, lane = tid & 63, wv = tid >> 6;
    const int bid = blockIdx.x;
    const int mt = bid / 6, nb = bid % 6;
    const size_t Mbase = (size_t)mt * 128;
    const int n0 = nb * 128;
    const int wm = wv >> 1, wn = wv & 1;
    const int c = lane & 15, g = lane >> 4;
    const int r8 = lane >> 3, chv = lane & 7;

    f32x4 acc[4][4];
#pragma unroll
    for (int a = 0; a < 4; ++a)
#pragma unroll
        for (int b = 0; b < 4; ++b) acc[a][b] = f32x4{0.f, 0.f, 0.f, 0.f};

    auto stage = [&](int step, int bsel) {
        const f16* As = X + Mbase * 256 + step * 64;
        const f16* Bs = win + (size_t)n0 * 256 + step * 64;
#pragma unroll
        for (int q = 0; q < 4; ++q) {
            int ia = wv * 4 + q;
            int row = ia * 8 + r8;
            int chs = chv ^ (row & 7);
            __builtin_amdgcn_global_load_lds(
                (const __attribute__((address_space(1))) unsigned int*)(As + (size_t)row * 256 + chs * 8),
                (__attribute__((address_space(3))) unsigned int*)(sm + bsel * 32768 + ia * 1024),
                16, 0, 0);
            __builtin_amdgcn_global_load_lds(
                (const __attribute__((address_space(1))) unsigned int*)(Bs + (size_t)row * 256 + chs * 8),
                (__attribute__((address_space(3))) unsigned int*)(sm + bsel * 32768 + 16384 + ia * 1024),
                16, 0, 0);
        }
    };
    stage(0, 0);
    __syncthreads();
    for (int s = 0; s < 4; ++s) {
        int bsel = s & 1;
        if (s < 3) stage(s + 1, bsel ^ 1);
#pragma unroll
        for (int kk2 = 0; kk2 < 2; ++kk2) {
            half8 a[4], b[4];
#pragma unroll
            for (int mi = 0; mi < 4; ++mi) {
                int row = wm * 64 + mi * 16 + c;
                a[mi] = *(half8*)(sm + bsel * 32768 + row * 128 + ((kk2 * 64 + g * 16) ^ ((row & 7) << 4)));
            }
#pragma unroll
            for (int nt = 0; nt < 4; ++nt) {
                int row = wn * 64 + nt * 16 + c;
                b[nt] = *(half8*)(sm + bsel * 32768 + 16384 + row * 128 + ((kk2 * 64 + g * 16) ^ ((row & 7) << 4)));
            }
#pragma unroll
            for (int mi = 0; mi < 4; ++mi)
#pragma unroll
                for (int nt = 0; nt < 4; ++nt)
                    acc[mi][nt] = MFMA32(a[mi], b[nt], acc[mi][nt]);
        }
        __syncthreads();
    }

    const f32x4 z4 = {0.f, 0.f, 0.f, 0.f};
    half4 idf;
#pragma unroll
    for (int j = 0; j < 4; ++j) idf[j] = (f16)((g * 4 + j == c) ? 1.f : 0.f);

    if (n0 < 512) {
        // Q,K: transpose via identity mfma, store row-major QK[t][512]
#pragma unroll
        for (int mi = 0; mi < 4; ++mi)
#pragma unroll
            for (int nt = 0; nt < 4; ++nt) {
                int n = n0 + wn * 64 + nt * 16 + c;
                float bias = inb[n];
                half4 h;
#pragma unroll
                for (int r = 0; r < 4; ++r) h[r] = (f16)(acc[mi][nt][r] + bias);
                f32x4 t = MFMA16(h, idf, z4);      // C/D-as-A (=T^T) times I -> transposed tile
                half4 o;
#pragma unroll
                for (int r = 0; r < 4; ++r) o[r] = (f16)t[r];
                size_t tok = Mbase + wm * 64 + mi * 16 + c;       // col of transposed tile = m
                *(half4*)(QK + tok * 512 + (n0 + wn * 64 + nt * 16 + g * 4)) = o;
            }
    } else {
        // V: store [win][d][t] directly from C/D (rows = 4 contiguous tokens)
#pragma unroll
        for (int mi = 0; mi < 4; ++mi)
#pragma unroll
            for (int nt = 0; nt < 4; ++nt) {
                int n = n0 + wn * 64 + nt * 16 + c;
                float bias = inb[n];
                half4 h;
#pragma unroll
                for (int r = 0; r < 4; ++r) h[r] = (f16)(acc[mi][nt][r] + bias);
                int d = n - 512;
                size_t tokb = Mbase + wm * 64 + mi * 16;          // window-aligned
                size_t winI = tokb >> 4;
                *(half4*)(VT + winI * 4096 + (size_t)d * 16 + g * 4) = h;
            }
    }
}

// ---------------- k3: attention + out-proj + proj + GELU -> G[t][256] f16 ----------------
__global__ __launch_bounds__(256, 3)
void k3_attn(const f16* __restrict__ QK, const f16* __restrict__ VT,
             const f16* __restrict__ wout, const f16* __restrict__ wproj,
             const float* __restrict__ outb, const float* __restrict__ projb,
             f16* __restrict__ G) {
    __shared__ __align__(16) char sm[32768];   // 2 x 16KB weight chunks [32 n][256 d], 8B-XOR swizzled
    const int tid = threadIdx.x, lane = tid & 63, wv = tid >> 6;
    const int c = lane & 15, g = lane >> 4;
    const size_t win = (size_t)blockIdx.x * 4 + wv;
    const f16* qrow = QK + (win * 16 + c) * 512;
    const f32x4 z4 = {0.f, 0.f, 0.f, 0.f};

    const int nl = tid >> 3, seg = tid & 7;
    const int swz = (nl & 7) << 3;
    auto stageW = [&](const f16* mat, int rc, int bsel) {
        const f16* src = mat + ((size_t)(rc * 32 + nl)) * 256 + seg * 32;
        char* dst = sm + bsel * 16384 + nl * 512;
#pragma unroll
        for (int i = 0; i < 4; ++i) {
            uint4 u = *(const uint4*)(src + i * 8);
            int b0 = (seg * 64 + i * 16) ^ swz;
            int b1 = (seg * 64 + i * 16 + 8) ^ swz;
            *(uint2*)(dst + b0) = make_uint2(u.x, u.y);
            *(uint2*)(dst + b1) = make_uint2(u.z, u.w);
        }
    };

    stageW(wout, 0, 0);   // chunk 0 in flight under attention

    // ---- attention, all in registers ----
    half4 of16[4][4];
#pragma unroll
    for (int hq = 0; hq < 4; ++hq) {
        half8 af0 = *(const half8*)(qrow + 256 + hq * 64 + g * 8);
        half8 af1 = *(const half8*)(qrow + 256 + hq * 64 + 32 + g * 8);
        half8 bq0 = *(const half8*)(qrow + hq * 64 + g * 8);
        half8 bq1 = *(const half8*)(qrow + hq * 64 + 32 + g * 8);
        f32x4 sacc = MFMA32(af0, bq0, z4);     // S^T[k_tok][q]
        sacc = MFMA32(af1, bq1, sacc);
        float s0 = sacc[0] * 0.125f, s1 = sacc[1] * 0.125f;
        float s2 = sacc[2] * 0.125f, s3 = sacc[3] * 0.125f;
        float mx = fmaxf(fmaxf(s0, s1), fmaxf(s2, s3));
        mx = fmaxf(mx, __shfl_xor(mx, 16));
        mx = fmaxf(mx, __shfl_xor(mx, 32));
        float p0 = __expf(s0 - mx), p1 = __expf(s1 - mx);
        float p2 = __expf(s2 - mx), p3 = __expf(s3 - mx);
        float sum = p0 + p1 + p2 + p3;
        sum += __shfl_xor(sum, 16);
        sum += __shfl_xor(sum, 32);
        float inv = 1.f / sum;
        half4 pf;
        pf[0] = (f16)(p0 * inv); pf[1] = (f16)(p1 * inv);
        pf[2] = (f16)(p2 * inv); pf[3] = (f16)(p3 * inv);
#pragma unroll
        for (int nt = 0; nt < 4; ++nt) {
            half4 vf = *(const half4*)(VT + win * 4096 + (size_t)(hq * 64 + nt * 16 + c) * 16 + g * 4);
            f32x4 o = MFMA16(vf, pf, z4);      // O^T[d][q]
            half4 oh;
#pragma unroll
            for (int r = 0; r < 4; ++r) oh[r] = (f16)o[r];
            of16[hq][nt] = oh;
        }
    }

    // ---- out-proj: OB^T[n][q] accumulated over 16 chunks of w_out rows ----
    f32x4 obacc[16];
#pragma unroll
    for (int i = 0; i < 16; ++i) obacc[i] = z4;
    __syncthreads();
#pragma unroll
    for (int ch = 0; ch < 8; ++ch) {
        if (ch < 7) stageW(wout, ch + 1, (ch + 1) & 1);
        else        stageW(wproj, 0, (ch + 1) & 1);
        int bsel = ch & 1;
#pragma unroll
        for (int ntl = 0; ntl < 2; ++ntl) {
            int nt2 = ch * 2 + ntl;
            int rowl = ntl * 16 + c;
            char* base = sm + bsel * 16384 + rowl * 512;
            int sw2 = (rowl & 7) << 3;
            f32x4 a = obacc[nt2];
#pragma unroll
            for (int hq = 0; hq < 4; ++hq)
#pragma unroll
                for (int dt = 0; dt < 4; ++dt) {
                    half4 wf = *(const half4*)(base + (((hq * 64 + dt * 16 + g * 4) * 2) ^ sw2));
                    a = MFMA16(wf, of16[hq][dt], a);
                }
            obacc[nt2] = a;
        }
        __syncthreads();
    }
    half4 obT[16];
#pragma unroll
    for (int nt = 0; nt < 16; ++nt) {
        f32x4 bv = *(const f32x4*)(outb + nt * 16 + g * 4);
        half4 h;
#pragma unroll
        for (int r = 0; r < 4; ++r) h[r] = (f16)(obacc[nt][r] + bv[r]);
        obT[nt] = h;
    }

    // ---- proj: Y^T[n_out][q] over 8 chunks of w_proj rows ----
    f32x4 yacc[16];
#pragma unroll
    for (int i = 0; i < 16; ++i) yacc[i] = z4;
#pragma unroll
    for (int pc = 0; pc < 8; ++pc) {
        if (pc < 7) stageW(wproj, pc + 1, (pc + 1) & 1);
        int bsel = pc & 1;
#pragma unroll
        for (int ntl = 0; ntl < 2; ++ntl) {
            int nt3 = pc * 2 + ntl;
            int rowl = ntl * 16 + c;
            char* base = sm + bsel * 16384 + rowl * 512;
            int sw2 = (rowl & 7) << 3;
            f32x4 a = yacc[nt3];
#pragma unroll
            for (int ntc = 0; ntc < 16; ++ntc) {
                half4 wf = *(const half4*)(base + (((ntc * 16 + g * 4) * 2) ^ sw2));
                a = MFMA16(wf, obT[ntc], a);
            }
            yacc[nt3] = a;
        }
        __syncthreads();
    }

    // ---- bias + exact GELU + store G ----
#pragma unroll
    for (int nt = 0; nt < 16; ++nt) {
        f32x4 bv = *(const f32x4*)(projb + nt * 16 + g * 4);
        half4 h;
#pragma unroll
        for (int r = 0; r < 4; ++r) {
            float x = yacc[nt][r] + bv[r];
            h[r] = (f16)(0.5f * x * (1.f + erff(x * 0.70710678118f)));
        }
        *(half4*)(G + (win * 16 + c) * 256 + nt * 16 + g * 4) = h;
    }
}

// ---------------- k4: residual + NCHW scatter (no LDS, register-held G row) ----------------
__global__ __launch_bounds__(256, 4)
void k4_out(const f16* __restrict__ G, const float* __restrict__ feat, float* __restrict__ outp) {
    const int tid = threadIdx.x, lane = tid & 63, wid = tid >> 6;
    const int bid = blockIdx.x;
    const int jh = bid & 3, wi = (bid >> 2) & 31, bb = bid >> 7;
    const int h0 = wi * 4, w0 = jh * 32;
    const int wl = lane >> 1, hf = lane & 1;
    const int hh = wid;
    const int h = h0 + hh, w = w0 + wl;
    const bool ok = (h < 127) && (w < 127);
    const size_t bbase = (size_t)bb * (256 * 127 * 127);

    const int m = (wl >> 2) * 16 + hh * 4 + (wl & 3);
    const f16* grow = G + ((size_t)bid * 128 + m) * 256 + hf * 128;
    half8 vv[16];
#pragma unroll
    for (int i = 0; i < 16; ++i) vv[i] = *(const half8*)(grow + i * 8);

    if (ok) {
        const float* fp = feat + bbase + (size_t)(hf * 128) * 16129 + (size_t)h * 127 + w;
        float* op = outp + bbase + (size_t)(hf * 128) * 16129 + (size_t)h * 127 + w;
#pragma unroll 4
        for (int i = 0; i < 32; ++i) {
#pragma unroll
            for (int j = 0; j < 4; ++j) {
                int ci = i * 4 + j;
                float val = (float)vv[ci >> 3][ci & 7];
                size_t off = (size_t)ci * 16129;
                op[off] = fp[off] + val;
            }
        }
    }
}

extern "C" void kernel_launch(void* const* d_in, const int* in_sizes, int n_in,
                              void* d_out, int out_size, void* d_ws, size_t ws_size,
                              hipStream_t stream) {
    const float* feat   = (const float*)d_in[0];
    const float* ln_w   = (const float*)d_in[1];
    const float* ln_b   = (const float*)d_in[2];
    const float* in_w   = (const float*)d_in[3];
    const float* in_b   = (const float*)d_in[4];
    const float* out_w  = (const float*)d_in[5];
    const float* out_b  = (const float*)d_in[6];
    const float* proj_w = (const float*)d_in[7];
    const float* proj_b = (const float*)d_in[8];

    f16* W  = (f16*)d_ws;
    f16* Xb  = W + X0;
    f16* QKb = W + QK0;
    f16* VTb = W + VT0;
    f16* Gb  = Xb;   // reuse X region for G (X dead after k2)

    k0_cast<<<768, 256, 0, stream>>>(in_w, out_w, proj_w, W);
    k1_pack<<<1024, 256, 0, stream>>>(feat, ln_w, ln_b, Xb);
    k2_qkv<<<6144, 256, 0, stream>>>(Xb, W + W_IN0, in_b, QKb, VTb);
    k3_attn<<<2048, 256, 0, stream>>>(QKb, VTb, W + W_OUT0, W + W_PROJ0, out_b, proj_b, Gb);
    k4_out<<<1024, 256, 0, stream>>>(Gb, feat, (float*)d_out);
}